// Round 14
// baseline (321.943 us; speedup 1.0000x reference)
//
#include <hip/hip_runtime.h>
#include <hip/hip_bf16.h>
#include <stdint.h>

#define D 1024
#define NSUP 256
#define ROWS 16384      // 4*4096
#define MB 32           // rows per block
#define LTHREADS 512    // 8 waves = 2 waves/SIMD -> per-wave reg budget up to 256
#define LGRID (ROWS / MB)   // 512 blocks

typedef __attribute__((__ext_vector_type__(8))) __bf16 bf16x8;
typedef __attribute__((__ext_vector_type__(4))) float f32x4;

#define MFMA16(a, b, c) __builtin_amdgcn_mfma_f32_16x16x32_bf16((a), (b), (c), 0, 0, 0)

static __device__ __forceinline__ uint16_t bf16bits(float f) {
    __bf16 b = (__bf16)f;
    return *(uint16_t*)&b;
}

__global__ void cast_k_kernel(const float* __restrict__ K, __bf16* __restrict__ Kb) {
    int i = (blockIdx.x * 256 + threadIdx.x) * 4;
    float4 v = *(const float4*)(K + i);
    __bf16 o[4] __attribute__((aligned(8)));
    o[0] = (__bf16)v.x; o[1] = (__bf16)v.y; o[2] = (__bf16)v.z; o[3] = (__bf16)v.w;
    *(uint2*)(Kb + i) = *(const uint2*)o;
}

// V [4][256][1024] f32 -> Vt [4][1024][256] bf16
__global__ void transpose_v_kernel(const float* __restrict__ V, __bf16* __restrict__ Vt) {
    __shared__ __bf16 tile[64][72];
    int l = blockIdx.z;
    int d0 = blockIdx.x * 64, n0 = blockIdx.y * 64;
    const float* Vl = V + (size_t)l * NSUP * D;
    __bf16* Vtl = Vt + (size_t)l * D * NSUP;
    for (int j = 0; j < 16; ++j) {
        int idx = j * 256 + threadIdx.x;
        int n_l = idx >> 6, d_l = idx & 63;
        tile[d_l][n_l] = (__bf16)Vl[(size_t)(n0 + n_l) * D + d0 + d_l];
    }
    __syncthreads();
    for (int j = 0; j < 16; ++j) {
        int idx = j * 256 + threadIdx.x;
        int d_l = idx >> 6, n_l = idx & 63;
        Vtl[(size_t)(d0 + d_l) * NSUP + n0 + n_l] = tile[d_l][n_l];
    }
}

// One CleanUpKV layer. 512 thr / 8 waves / 32 rows / LDS ~50K.
// STRATEGY (r14): deep ILP at 2 waves/SIMD. The unified VGPR+AGPR budget is
// 256/wave at this occupancy (r3-r13 evidence: 2-block residency requires
// <=128 total; 1024-thr blocks force 128 and spill at 64 arch). So each
// phase-chunk's full B-operand slice (16 x bf16x8 = 64 VGPR) is batch-loaded
// into double-buffered register arrays one chunk AHEAD - L2 latency hides
// under the previous chunk's 32 MFMAs instead of stalling every k-step.
// h between layers: RAW bf16, PRE-SWIZZLED global image (byte
// row*2048 + ((col*2)^((row&7)<<4))) -> staging is pure global_load_lds.
// rn passed via rnbuf, folded into softmax exp. No softmax max-pass
// (|score*rn| <= |k_row| ~ 34, exp2 arg <= 50, f32-safe).
template<bool IN_F32, bool OUT_F32>
__global__ void __launch_bounds__(LTHREADS)
layer_kernel(const void* __restrict__ h_in, void* __restrict__ h_out,
             const __bf16* __restrict__ Kb, const __bf16* __restrict__ Vt,
             float* __restrict__ rnbuf) {
    __shared__ __align__(16) char pool[49152];   // buf0 16K | buf1 16K | w 16K
    __shared__ float red[MB][8];
    __shared__ float rnin[MB];
    char* wbuf = pool + 32768;

    const int tid = threadIdx.x;
    const int lane = tid & 63;
    const int wv = tid >> 6;            // wave 0..7
    const int llo = lane & 15, lhi = lane >> 4;
    const int swzk = (llo & 7) << 4;    // swizzle key for rows *16+llo
    const int row0 = blockIdx.x * MB;

    // ---- rn input: layer0 computes from x; others load from rnbuf ----
    if constexpr (IN_F32) {
        const float4* x4 = (const float4*)h_in;
        #pragma unroll
        for (int rr = 0; rr < 4; ++rr) {
            int row = wv * 4 + rr;
            const float4* p = x4 + (size_t)(row0 + row) * 256;
            float s = 0.f;
            #pragma unroll
            for (int j = 0; j < 4; ++j) {
                float4 v = p[j * 64 + lane];
                s += v.x * v.x + v.y * v.y + v.z * v.z + v.w * v.w;
            }
            #pragma unroll
            for (int off = 1; off < 64; off <<= 1) s += __shfl_xor(s, off);
            if (lane == 0) rnin[row] = 1.f / (sqrtf(s) + 1e-9f);
        }
        __syncthreads();   // rnin ready for scaled staging
    } else {
        if (tid < MB) rnin[tid] = rnbuf[row0 + tid];
    }

    // ---- staging of one 32x256-col chunk (16KB) ----
    auto stage = [&](int dc) {
        char* buf = pool + (dc & 1) * 16384;
        if constexpr (IN_F32) {
            int srow = tid >> 4, c16 = tid & 15;
            int key = (srow & 7) << 4;
            const float4* p = (const float4*)((const float*)h_in
                              + (size_t)(row0 + srow) * D + dc * 256 + c16 * 16);
            float rn = rnin[srow];
            __bf16 t[16] __attribute__((aligned(16)));
            #pragma unroll
            for (int q = 0; q < 4; ++q) {
                float4 v = p[q];
                t[4 * q + 0] = (__bf16)(v.x * rn); t[4 * q + 1] = (__bf16)(v.y * rn);
                t[4 * q + 2] = (__bf16)(v.z * rn); t[4 * q + 3] = (__bf16)(v.w * rn);
            }
            int b0 = c16 * 32;
            *(bf16x8*)(buf + srow * 512 + (b0 ^ key))        = *(const bf16x8*)(t);
            *(bf16x8*)(buf + srow * 512 + ((b0 + 16) ^ key)) = *(const bf16x8*)(t + 8);
        } else {
            #pragma unroll
            for (int c = 0; c < 2; ++c) {
                int L = (c * 512 + tid) * 16;
                int row = L >> 9;
                int b = L & 511;
                const char* g = (const char*)h_in + (size_t)(row0 + row) * 2048 + dc * 512 + b;
                __builtin_amdgcn_global_load_lds(
                    (const __attribute__((address_space(1))) uint32_t*)g,
                    (__attribute__((address_space(3))) uint32_t*)(pool + (dc & 1) * 16384 + L), 16, 0, 0);
            }
        }
    };

    // ---------- Phase A: scores[32x256] = h @ K^T; wave cols [wv*32,+32) ----------
    f32x4 acc[2][2];
    #pragma unroll
    for (int rf = 0; rf < 2; ++rf)
        #pragma unroll
        for (int cf = 0; cf < 2; ++cf)
            acc[rf][cf] = (f32x4){0.f, 0.f, 0.f, 0.f};

    const __bf16* kbase = Kb + (size_t)(wv * 32 + llo) * D + lhi * 8;
    bf16x8 kfrA[16], kfrB[16];

    auto loadK = [&](bf16x8 (&dst)[16], int dc) {
        const __bf16* kn = kbase + dc * 256;
        #pragma unroll
        for (int cf = 0; cf < 2; ++cf)
            #pragma unroll
            for (int kk = 0; kk < 8; ++kk)
                dst[cf * 8 + kk] = *(const bf16x8*)(kn + (size_t)cf * 16 * D + kk * 32);
    };
    auto runA = [&](int dc, bf16x8 (&cur)[16], bf16x8 (&nxt)[16], bool pre) {
        if (dc < 3) stage(dc + 1);
        if (pre) loadK(nxt, dc + 1);            // in flight across this chunk's MFMAs
        const char* hb = pool + (dc & 1) * 16384;
        #pragma unroll
        for (int kk = 0; kk < 8; ++kk) {
            bf16x8 a0 = *(const bf16x8*)(hb + llo * 512 + ((kk * 64 + lhi * 16) ^ swzk));
            bf16x8 a1 = *(const bf16x8*)(hb + (16 + llo) * 512 + ((kk * 64 + lhi * 16) ^ swzk));
            #pragma unroll
            for (int cf = 0; cf < 2; ++cf) {
                acc[0][cf] = MFMA16(a0, cur[cf * 8 + kk], acc[0][cf]);
                acc[1][cf] = MFMA16(a1, cur[cf * 8 + kk], acc[1][cf]);
            }
        }
        __syncthreads();   // drains stage(dc+1) + protects h dbuf reuse
    };

    stage(0);
    loadK(kfrA, 0);
    __syncthreads();
    runA(0, kfrA, kfrB, true);
    runA(1, kfrB, kfrA, true);
    runA(2, kfrA, kfrB, true);
    runA(3, kfrB, kfrA, false);

    // ---- Phase C chunk-0 V preload: hides L2 latency under softmax VALU ----
    const __bf16* vbase = Vt + (size_t)(wv * 128 + llo) * NSUP + lhi * 8;
    bf16x8 vfrA[16], vfrB[16];
    auto loadV = [&](bf16x8 (&dst)[16], int ch) {
        const __bf16* vn = vbase + (size_t)(ch * 32) * NSUP;
        #pragma unroll
        for (int c2 = 0; c2 < 2; ++c2)
            #pragma unroll
            for (int kk = 0; kk < 8; ++kk)
                dst[c2 * 8 + kk] = *(const bf16x8*)(vn + (size_t)c2 * 16 * NSUP + kk * 32);
    };
    loadV(vfrA, 0);

    // ---------- Phase B: softmax (rn folded, no max-pass) ----------
    float ee[2][2][4];
    #pragma unroll
    for (int rf = 0; rf < 2; ++rf)
        #pragma unroll
        for (int r = 0; r < 4; ++r) {
            int row = rf * 16 + lhi * 4 + r;
            float sc = (IN_F32 ? 1.f : rnin[row]) * 1.44269504f;
            float e0 = exp2f(acc[rf][0][r] * sc);
            float e1 = exp2f(acc[rf][1][r] * sc);
            ee[rf][0][r] = e0; ee[rf][1][r] = e1;
            float s = e0 + e1;
            s += __shfl_xor(s, 1); s += __shfl_xor(s, 2);
            s += __shfl_xor(s, 4); s += __shfl_xor(s, 8);
            if (llo == 0) red[row][wv] = s;
        }
    __syncthreads();   // exp partials visible
    #pragma unroll
    for (int rf = 0; rf < 2; ++rf)
        #pragma unroll
        for (int r = 0; r < 4; ++r) {
            int row = rf * 16 + lhi * 4 + r;
            const f32x4* rp = (const f32x4*)&red[row][0];
            f32x4 s0 = rp[0], s1 = rp[1];
            float S = (s0[0] + s0[1] + s0[2] + s0[3]) + (s1[0] + s1[1] + s1[2] + s1[3]);
            float inv = 1.f / S;
            #pragma unroll
            for (int cf = 0; cf < 2; ++cf) {
                int col = wv * 32 + cf * 16 + llo;
                *(__bf16*)(wbuf + row * 512 + ((col * 2) ^ ((row & 7) << 4))) =
                    (__bf16)(ee[rf][cf][r] * inv);
            }
        }
    __syncthreads();   // w visible

    // ---------- Phase C: out[32x1024] = w @ V; wave d-cols [wv*128,+128) ----------
    float sql[2][4];
    #pragma unroll
    for (int rf = 0; rf < 2; ++rf)
        #pragma unroll
        for (int r = 0; r < 4; ++r) sql[rf][r] = 0.f;

    auto runC = [&](int ch, bf16x8 (&cur)[16], bf16x8 (&nxt)[16], bool pre) {
        if (pre) loadV(nxt, ch + 1);            // in flight across this chunk's MFMAs
        f32x4 acc2[2][2];
        #pragma unroll
        for (int rf = 0; rf < 2; ++rf)
            #pragma unroll
            for (int c2 = 0; c2 < 2; ++c2)
                acc2[rf][c2] = (f32x4){0.f, 0.f, 0.f, 0.f};
        #pragma unroll
        for (int kk = 0; kk < 8; ++kk) {
            bf16x8 a0 = *(const bf16x8*)(wbuf + llo * 512 + ((kk * 64 + lhi * 16) ^ swzk));
            bf16x8 a1 = *(const bf16x8*)(wbuf + (16 + llo) * 512 + ((kk * 64 + lhi * 16) ^ swzk));
            #pragma unroll
            for (int c2 = 0; c2 < 2; ++c2) {
                acc2[0][c2] = MFMA16(a0, cur[c2 * 8 + kk], acc2[0][c2]);
                acc2[1][c2] = MFMA16(a1, cur[c2 * 8 + kk], acc2[1][c2]);
            }
        }
        #pragma unroll
        for (int rf = 0; rf < 2; ++rf)
            #pragma unroll
            for (int c2 = 0; c2 < 2; ++c2)
                #pragma unroll
                for (int r = 0; r < 4; ++r) {
                    int row = rf * 16 + lhi * 4 + r;
                    int col = wv * 128 + ch * 32 + c2 * 16 + llo;
                    float v = acc2[rf][c2][r];
                    sql[rf][r] += v * v;
                    if constexpr (OUT_F32) {
                        ((float*)h_out)[(size_t)(row0 + row) * D + col] = v;
                    } else {
                        *(uint16_t*)((char*)h_out + (size_t)(row0 + row) * 2048
                                     + ((col * 2) ^ ((row & 7) << 4))) = bf16bits(v);
                    }
                }
    };
    runC(0, vfrA, vfrB, true);
    runC(1, vfrB, vfrA, true);
    runC(2, vfrA, vfrB, true);
    runC(3, vfrB, vfrA, false);

    // ---------- epilogue: next-layer rn from f32 accumulators ----------
    if constexpr (!OUT_F32) {
        #pragma unroll
        for (int rf = 0; rf < 2; ++rf)
            #pragma unroll
            for (int r = 0; r < 4; ++r) {
                float s = sql[rf][r];
                s += __shfl_xor(s, 1); s += __shfl_xor(s, 2);
                s += __shfl_xor(s, 4); s += __shfl_xor(s, 8);
                if (llo == 0) red[rf * 16 + lhi * 4 + r][wv] = s;
            }
        __syncthreads();
        if (tid < MB) {
            const f32x4* rp = (const f32x4*)&red[tid][0];
            f32x4 s0 = rp[0], s1 = rp[1];
            float S = (s0[0] + s0[1] + s0[2] + s0[3]) + (s1[0] + s1[1] + s1[2] + s1[3]);
            rnbuf[row0 + tid] = 1.f / (sqrtf(S) + 1e-9f);
        }
    }
}

extern "C" void kernel_launch(void* const* d_in, const int* in_sizes, int n_in,
                              void* d_out, int out_size, void* d_ws, size_t ws_size,
                              hipStream_t stream) {
    const float* x = (const float*)d_in[0];
    const float* keys = (const float*)d_in[1];
    const float* values = (const float*)d_in[2];
    float* out = (float*)d_out;

    char* ws = (char*)d_ws;
    char*   h  = ws;                            // 16384*2048 = 33554432 B (raw bf16, swizzled)
    __bf16* Kb = (__bf16*)(ws + 33554432);      // 2 MB
    __bf16* Vt = (__bf16*)(ws + 35651584);      // 2 MB
    float*  rn = (float*)(ws + 37748736);       // 64 KB

    cast_k_kernel<<<1024, 256, 0, stream>>>(keys, Kb);
    transpose_v_kernel<<<dim3(16, 4, 4), 256, 0, stream>>>(values, Vt);

    const int LS = NSUP * D;
    layer_kernel<true,  false><<<LGRID, LTHREADS, 0, stream>>>(x, h, Kb,          Vt,          rn);
    layer_kernel<false, false><<<LGRID, LTHREADS, 0, stream>>>(h, h, Kb + LS,     Vt + LS,     rn);
    layer_kernel<false, false><<<LGRID, LTHREADS, 0, stream>>>(h, h, Kb + 2 * LS, Vt + 2 * LS, rn);
    layer_kernel<false, true ><<<LGRID, LTHREADS, 0, stream>>>(h, out, Kb + 3 * LS, Vt + 3 * LS, rn);
}